// Round 13
// baseline (645.719 us; speedup 1.0000x reference)
//
#include <hip/hip_runtime.h>

// ---------------------------------------------------------------------------
// AWQ int4 dequant GEMM: out = x @ dequant(qweight, scales, qzeros) + bias
// M=4096, K=4096, N=11008, group=128
//   1) convert_x: fp32->bf16 A[M][K]
//   2) dequant_awq: int4 -> bf16 Bt[N][K]
//   3) gemm_bf16: 256x256xBK64, 8 waves (2Mx4N), per-wave 128x64.
//      A via LDS (2x32KB dbuf, XOR-swizzle, gload16); B fragments gathered
//      DIRECTLY global->register (SGPR base + 32b voffset, full-64B-line
//      pattern) -- removes B from the LDS port (the measured wall) and
//      moves it to the idle L2 pipe.  Counted vmcnt gates (8/4/0).
// ---------------------------------------------------------------------------

typedef __bf16 bf16x8 __attribute__((ext_vector_type(8)));
typedef float f32x4 __attribute__((ext_vector_type(4)));
typedef unsigned short ushort8 __attribute__((ext_vector_type(8)));

__device__ __forceinline__ unsigned short f2bf(float f) {
  unsigned int u = __builtin_bit_cast(unsigned int, f);
  u += 0x7FFFu + ((u >> 16) & 1u);
  return (unsigned short)(u >> 16);
}

__device__ __forceinline__ void gload16(const void* g, void* l) {
  __builtin_amdgcn_global_load_lds(
      (const __attribute__((address_space(1))) unsigned int*)g,
      (__attribute__((address_space(3))) unsigned int*)l, 16, 0, 0);
}

// ---------------------------------------------------------------------------
// Kernel 1: x fp32 -> A bf16
// ---------------------------------------------------------------------------
__global__ __launch_bounds__(256) void convert_x(const float* __restrict__ x,
                                                 unsigned short* __restrict__ A,
                                                 long long n8) {
  for (long long idx = (long long)blockIdx.x * 256 + threadIdx.x; idx < n8;
       idx += (long long)gridDim.x * 256) {
    float4 u = ((const float4*)x)[2 * idx];
    float4 v = ((const float4*)x)[2 * idx + 1];
    ushort8 o;
    o[0] = f2bf(u.x); o[1] = f2bf(u.y); o[2] = f2bf(u.z); o[3] = f2bf(u.w);
    o[4] = f2bf(v.x); o[5] = f2bf(v.y); o[6] = f2bf(v.z); o[7] = f2bf(v.w);
    ((ushort8*)A)[idx] = o;
  }
}

// ---------------------------------------------------------------------------
// Kernel 2: AWQ dequant + transpose -> Bt bf16 [N][K]
// ---------------------------------------------------------------------------
__global__ __launch_bounds__(256) void dequant_awq(const int* __restrict__ qw,
                                                   const float* __restrict__ sc,
                                                   const int* __restrict__ qz,
                                                   unsigned short* __restrict__ Bt,
                                                   int K, int N) {
  const int n8w = N >> 3;
  const int tiles_n = N >> 6;
  const int tk = blockIdx.x / tiles_n;
  const int tn = blockIdx.x % tiles_n;
  const int k0 = tk << 6, n0 = tn << 6;
  const int g = k0 >> 7;
  __shared__ unsigned short tile[64][72];
  __shared__ float s_s[64];
  __shared__ float s_z[64];
  const int t = threadIdx.x;
  if (t < 64) {
    s_s[t] = sc[(size_t)g * N + n0 + t];
  } else if (t < 72) {
    const int j = t - 64;
    const int zq = qz[(size_t)g * n8w + (n0 >> 3) + j];
    s_z[j * 8 + 0] = (float)((zq >> 0) & 0xF);
    s_z[j * 8 + 1] = (float)((zq >> 16) & 0xF);
    s_z[j * 8 + 2] = (float)((zq >> 4) & 0xF);
    s_z[j * 8 + 3] = (float)((zq >> 20) & 0xF);
    s_z[j * 8 + 4] = (float)((zq >> 8) & 0xF);
    s_z[j * 8 + 5] = (float)((zq >> 24) & 0xF);
    s_z[j * 8 + 6] = (float)((zq >> 12) & 0xF);
    s_z[j * 8 + 7] = (float)((zq >> 28) & 0xF);
  }
  __syncthreads();
#pragma unroll
  for (int r = 0; r < 2; ++r) {
    const int d = (r << 8) + t;
    const int kk = d >> 3, j = d & 7;
    const int q = qw[(size_t)(k0 + kk) * n8w + (n0 >> 3) + j];
    const int base = j << 3;
    ushort8 o;
    o[0] = f2bf(((float)((q >> 0) & 0xF) - s_z[base + 0]) * s_s[base + 0]);
    o[1] = f2bf(((float)((q >> 16) & 0xF) - s_z[base + 1]) * s_s[base + 1]);
    o[2] = f2bf(((float)((q >> 4) & 0xF) - s_z[base + 2]) * s_s[base + 2]);
    o[3] = f2bf(((float)((q >> 20) & 0xF) - s_z[base + 3]) * s_s[base + 3]);
    o[4] = f2bf(((float)((q >> 8) & 0xF) - s_z[base + 4]) * s_s[base + 4]);
    o[5] = f2bf(((float)((q >> 24) & 0xF) - s_z[base + 5]) * s_s[base + 5]);
    o[6] = f2bf(((float)((q >> 12) & 0xF) - s_z[base + 6]) * s_s[base + 6]);
    o[7] = f2bf(((float)((q >> 28) & 0xF) - s_z[base + 7]) * s_s[base + 7]);
    *(ushort8*)&tile[kk][base] = o;
  }
  __syncthreads();
#pragma unroll
  for (int r = 0; r < 2; ++r) {
    const int d = (r << 8) + t;
    const int nl = d >> 3, seg = d & 7;
    ushort8 o;
#pragma unroll
    for (int i = 0; i < 8; ++i) o[i] = tile[(seg << 3) + i][nl];
    *(ushort8*)&Bt[(size_t)(n0 + nl) * K + k0 + (seg << 3)] = o;
  }
}

// ---------------------------------------------------------------------------
// Kernel 3: 256x256xBK64; A via LDS, B direct global->reg gather.
// 8 waves (2M x 4N), per-wave 128x64 = acc[8][4] f32x4.
// LDS: 2 bufs x A[256][64] = 64 KiB.  Row = 8 chunks of 16B; phys chunk =
// logical ^ (row&7) (R12-proven 0-conflict); staged via pre-swizzled global
// source (linear LDS dest, rule #21).
// B: per-lane gather Bt[(bcol+wn*64+n*16+(lane&15))*K + k0 + kk*32 +
// (lane>>4)*8] -- same data addresses as the passing LDS path; lanes
// {r,r+16,r+32,r+48} cover one full 64B line.
// Tile t: issue B kk0(4), B kk1(4), stage A(t+1)(4 gload16) ->
// vmcnt(8): MFMA kk0 (a from lgkm(0) ds_reads) -> vmcnt(4): MFMA kk1 ->
// vmcnt(0) -> barrier.
// ---------------------------------------------------------------------------
#define BM 256
#define BN 256
#define BK 64

__global__ __launch_bounds__(512, 2) void gemm_bf16(const unsigned short* __restrict__ A,
                                                    const unsigned short* __restrict__ Bt,
                                                    const float* __restrict__ bias,
                                                    float* __restrict__ C,
                                                    int M, int N, int K) {
  __shared__ __align__(16) unsigned short sm[2][16384];  // 2 x 32 KiB (A only)
  const int tid = threadIdx.x;
  const int w = tid >> 6, lane = tid & 63;
  const int wm = w >> 2, wn = w & 3;

  // cluster mapping (R6-proven): per XCD, 4bm x 8bn = 32 slots
  const int nbm = M / BM;                       // 16
  const int nbn = N / BN;                       // 43
  const int nclu = ((nbm + 3) >> 2) * ((nbn + 7) >> 3);
  const int xcd = blockIdx.x & 7;
  const int slot = blockIdx.x >> 3;
  const int ci = xcd + 8 * (slot >> 5);
  if (ci >= nclu) return;
  const int t32 = slot & 31;
  const int bm = (ci & 3) * 4 + (t32 & 3);
  const int bn = (ci >> 2) * 8 + (t32 >> 2);
  if (bm >= nbm || bn >= nbn) return;
  const int brow = bm * BM, bcol = bn * BN;

  // ---- A staging (4 gload16/tile): thread t covers row i*64+(t>>3),
  // phys chunk t&7, source logical chunk (t&7)^((t>>3)&7).
  const int srow = tid >> 3;                    // 0..63
  const int schunk = (tid & 7) ^ (srow & 7);
  const unsigned short* pA = A + (size_t)(brow + srow) * K + schunk * 8;

  // ---- A fragment reads: row R = wm*128 + m*16 + (lane&15);
  // logical chunk kk*4+(lane>>4); phys = logical ^ (lane&7).
  const int aRowBase = (wm * 128 + (lane & 15)) * 64;  // shorts
  const int c0 = (((lane >> 4)) ^ (lane & 7)) * 8;     // kk=0 chunk, shorts
  const int c1 = ((4 + (lane >> 4)) ^ (lane & 7)) * 8; // kk=1 chunk, shorts

  // ---- B gather voffsets (bytes, 32-bit): advance +128 B per tile.
  const char* Bq = (const char*)Bt;
  unsigned int vb[4];
#pragma unroll
  for (int n = 0; n < 4; ++n)
    vb[n] = (unsigned int)((((size_t)(bcol + wn * 64 + n * 16 + (lane & 15)) * K)
                            + (size_t)((lane >> 4) * 8)) * 2);

  const int NKt = K / BK;  // 64

  f32x4 acc[8][4];
#pragma unroll
  for (int m = 0; m < 8; ++m)
#pragma unroll
    for (int n = 0; n < 4; ++n) acc[m][n] = (f32x4){0.f, 0.f, 0.f, 0.f};

  auto stage_A = [&](int kt) {
    const int buf = kt & 1;
    const size_t k0 = (size_t)kt * BK;
    unsigned short* dst = &sm[buf][w * 512];   // wave-uniform; lane*16B auto
#pragma unroll
    for (int i = 0; i < 4; ++i)
      gload16(pA + k0 + (size_t)(i * 64) * K, dst + i * 4096);
  };

  // prologue: stage A tile 0
  stage_A(0);
  asm volatile("s_waitcnt vmcnt(0)" ::: "memory");
  __builtin_amdgcn_s_barrier();

  for (int t = 0; t < NKt; ++t) {
    const unsigned short* bp = sm[t & 1];
    const bool more = (t + 1 < NKt);

    // issue B kk0 (4 loads)
    bf16x8 b[4][2];
#pragma unroll
    for (int n = 0; n < 4; ++n)
      b[n][0] = *(const bf16x8*)(Bq + vb[n]);
    __builtin_amdgcn_sched_barrier(0);
    // issue B kk1 (4 loads; +64 B = 32 shorts)
#pragma unroll
    for (int n = 0; n < 4; ++n)
      b[n][1] = *(const bf16x8*)(Bq + vb[n] + 64);
    __builtin_amdgcn_sched_barrier(0);
    // stage A(t+1) (4 gload_lds)
    if (more) stage_A(t + 1);
    __builtin_amdgcn_sched_barrier(0);

    // A fragments kk=0
    bf16x8 a[8];
#pragma unroll
    for (int m = 0; m < 8; ++m)
      a[m] = *(const bf16x8*)(bp + aRowBase + m * 1024 + c0);
    __builtin_amdgcn_sched_barrier(0);

    // gate: B kk0 landed (leave kk1 + stage outstanding)
    if (more) asm volatile("s_waitcnt vmcnt(8)" ::: "memory");
    else      asm volatile("s_waitcnt vmcnt(4)" ::: "memory");
    asm volatile("s_waitcnt lgkmcnt(0)" ::: "memory");
    __builtin_amdgcn_sched_barrier(0);
    __builtin_amdgcn_s_setprio(1);
#pragma unroll
    for (int m = 0; m < 8; ++m)
#pragma unroll
      for (int n = 0; n < 4; ++n)
        acc[m][n] = __builtin_amdgcn_mfma_f32_16x16x32_bf16(a[m], b[n][0], acc[m][n], 0, 0, 0);
    __builtin_amdgcn_s_setprio(0);
    __builtin_amdgcn_sched_barrier(0);

    // A fragments kk=1
#pragma unroll
    for (int m = 0; m < 8; ++m)
      a[m] = *(const bf16x8*)(bp + aRowBase + m * 1024 + c1);
    __builtin_amdgcn_sched_barrier(0);

    // gate: B kk1 landed (leave stage outstanding)
    if (more) asm volatile("s_waitcnt vmcnt(4)" ::: "memory");
    else      asm volatile("s_waitcnt vmcnt(0)" ::: "memory");
    asm volatile("s_waitcnt lgkmcnt(0)" ::: "memory");
    __builtin_amdgcn_sched_barrier(0);
    __builtin_amdgcn_s_setprio(1);
#pragma unroll
    for (int m = 0; m < 8; ++m)
#pragma unroll
      for (int n = 0; n < 4; ++n)
        acc[m][n] = __builtin_amdgcn_mfma_f32_16x16x32_bf16(a[m], b[n][1], acc[m][n], 0, 0, 0);
    __builtin_amdgcn_s_setprio(0);
    __builtin_amdgcn_sched_barrier(0);

    // advance B voffsets; drain stage (issued ~1 tile ago); tile boundary
#pragma unroll
    for (int n = 0; n < 4; ++n) vb[n] += 128;
    asm volatile("s_waitcnt vmcnt(0)" ::: "memory");
    __builtin_amdgcn_s_barrier();
  }

  // epilogue: C/D layout col=lane&15, row=(lane>>4)*4+reg
#pragma unroll
  for (int n = 0; n < 4; ++n) {
    const int col = bcol + wn * 64 + n * 16 + (lane & 15);
    const float bv = bias[col];
#pragma unroll
    for (int m = 0; m < 8; ++m) {
      const int row0 = brow + wm * 128 + m * 16 + ((lane >> 4) << 2);
#pragma unroll
      for (int q = 0; q < 4; ++q)
        C[(size_t)(row0 + q) * N + col] = acc[m][n][q] + bv;
    }
  }
}

// ---------------------------------------------------------------------------
extern "C" void kernel_launch(void* const* d_in, const int* in_sizes, int n_in,
                              void* d_out, int out_size, void* d_ws, size_t ws_size,
                              hipStream_t stream) {
  const float* x = (const float*)d_in[0];
  const int* qw = (const int*)d_in[1];
  const float* sc = (const float*)d_in[2];
  const int* qz = (const int*)d_in[3];
  const float* bias = (const float*)d_in[4];
  float* out = (float*)d_out;

  const int N = in_sizes[4];                              // 11008
  const int K = (int)(((long long)in_sizes[1] * 8) / N);  // 4096
  const int M = in_sizes[0] / K;                          // 4096

  const size_t a_elems = (size_t)M * K;
  const size_t b_elems = (size_t)N * K;
  const size_t need = (a_elems + b_elems) * sizeof(unsigned short);
  if (ws_size < need) return;

  unsigned short* A = (unsigned short*)d_ws;
  unsigned short* Bt = A + a_elems;

  convert_x<<<2048, 256, 0, stream>>>(x, A, (long long)(a_elems / 8));
  dequant_awq<<<(K / 64) * (N / 64), 256, 0, stream>>>(qw, sc, qz, Bt, K, N);

  const int nbm = M / BM, nbn = N / BN;
  const int nclu = ((nbm + 3) / 4) * ((nbn + 7) / 8);
  const int grid = 8 * 32 * ((nclu + 7) / 8);  // 768
  gemm_bf16<<<grid, 512, 0, stream>>>(A, Bt, bias, out, M, N, K);
}